// Round 1
// baseline (110.434 us; speedup 1.0000x reference)
//
#include <hip/hip_runtime.h>

// Problem constants (fixed by setup_inputs)
#define BSZ  4
#define CCH  320
#define HH   96
#define WW   192
#define NHEAD 16
#define NC   20          // channels per group = 320/16
#define DMAX 64
#define HWSZ (HH * WW)

// One block per (b, g, y) row. 192 threads, thread = x.
// rf row staged in LDS, zero-padded by DMAX on the left so shifts need no branch.
__global__ __launch_bounds__(192) void gwc_kernel(const float* __restrict__ lf,
                                                  const float* __restrict__ rf,
                                                  float* __restrict__ out) {
    __shared__ float rfs[(WW + DMAX) * NC];   // [x + 64][20]  = 20480 B

    const int tid = threadIdx.x;              // x in [0, 192)
    int bid = blockIdx.x;
    const int y = bid % HH;  bid /= HH;
    const int g = bid % NHEAD; bid /= NHEAD;
    const int b = bid;

    // zero the left pad region (64 slots * 20 ch)
    for (int i = tid; i < DMAX * NC; i += 192) rfs[i] = 0.0f;

    const size_t inbase = ((size_t)(b * CCH + g * NC) * HH + y) * WW + tid;

    float lfr[NC];
#pragma unroll
    for (int ch = 0; ch < NC; ++ch) {
        lfr[ch] = lf[inbase + (size_t)ch * HWSZ];
        rfs[(tid + DMAX) * NC + ch] = rf[inbase + (size_t)ch * HWSZ];
    }
    __syncthreads();

    // pack lf into float4s so the dot uses 5 x (float4 * float4)
    float4 l4[5];
#pragma unroll
    for (int j = 0; j < 5; ++j)
        l4[j] = make_float4(lfr[4 * j], lfr[4 * j + 1], lfr[4 * j + 2], lfr[4 * j + 3]);

    const float4* __restrict__ rw = (const float4*)rfs;  // 5 float4 per x-slot
    const float scale = 0.22360679774997896f;            // 1/sqrt(20)

    const size_t obase = ((size_t)(b * NHEAD + g) * DMAX) * HWSZ + (size_t)y * WW + tid;

#pragma unroll 4
    for (int d = 0; d < DMAX; ++d) {
        const int base4 = (tid + DMAX - d) * 5;  // float4 index of rf[x-d]
        float acc = 0.0f;
#pragma unroll
        for (int j = 0; j < 5; ++j) {
            const float4 r = rw[base4 + j];
            acc += l4[j].x * r.x + l4[j].y * r.y + l4[j].z * r.z + l4[j].w * r.w;
        }
        out[obase + (size_t)d * HWSZ] = acc * scale;
    }
}

extern "C" void kernel_launch(void* const* d_in, const int* in_sizes, int n_in,
                              void* d_out, int out_size, void* d_ws, size_t ws_size,
                              hipStream_t stream) {
    const float* lf = (const float*)d_in[0];
    const float* rf = (const float*)d_in[1];
    float* out = (float*)d_out;

    const int grid = BSZ * NHEAD * HH;  // 6144 blocks, one per (b,g,y)
    gwc_kernel<<<grid, 192, 0, stream>>>(lf, rf, out);
}